// Round 23
// baseline (123.997 us; speedup 1.0000x reference)
//
#include <hip/hip_runtime.h>
#include <hip/hip_bf16.h>
#include <cstdint>
#include <cstddef>

#define T_TOTAL 32768
#define F_IN    73
#define H_FNN   512
#define D_FNN   256
#define H_RNN   128
#define G4      512
#define SEG     4
#define BURN    28
#define STEPS   (SEG + BURN)      // 32
#define CPB     16               // chains per lstm block (one per MFMA D-column)
#define NLSTM   512              // 512 x 16 chains x 4 steps = 32768
#define KEXT    160              // 128 (h) + 32 (x block: 25 feats + bias + pad)
#define HBROW   184              // hB row stride (92 dwords = 28 mod 32 -> <=2-way banks)
#define OBROW   134              // outb row stride in shorts (67 dwords = 3 mod 32)
#define OUT_COLS 384
#define KP1     96

typedef short bf16x8 __attribute__((ext_vector_type(8)));
typedef float f32x4  __attribute__((ext_vector_type(4)));

// ---------------- helpers ----------------

__device__ __forceinline__ float fast_sigmoid(float x) {
    float e = __expf(-x);
    return __builtin_amdgcn_rcpf(1.f + e);
}
__device__ __forceinline__ float fast_tanh(float x) {
    float e = __expf(2.f * x);
    return 1.f - 2.f * __builtin_amdgcn_rcpf(e + 1.f);
}

// ---------------- prep: W1b, W2b, Whh4 (K=160 concat), Xd (validated R22) ----------------

#define P_W1   (H_FNN * KP1)       // 49152
#define P_W2   (D_FNN * H_FNN)     // 131072
#define P_WHH4 (G4 * KEXT)         // 81920
#define P_XD   (T_TOTAL * 32)      // 1048576
#define P_TOT  (P_W1 + P_W2 + P_WHH4 + P_XD)

__global__ void prep_kernel(
    const float* __restrict__ features, const float* __restrict__ W1,
    const float* __restrict__ W2,       const float* __restrict__ W_hh,
    const float* __restrict__ W_ih,     const float* __restrict__ b_ih,
    const float* __restrict__ b_hh,
    __hip_bfloat16* __restrict__ W1b,   __hip_bfloat16* __restrict__ W2b,
    __hip_bfloat16* __restrict__ Whh4,  __hip_bfloat16* __restrict__ Xd)
{
    int idx = blockIdx.x * 256 + threadIdx.x;
    if (idx >= P_TOT) return;
    if (idx < P_W1) {
        int n = idx / KP1, k = idx % KP1;
        W1b[idx] = __float2bfloat16(k < F_IN ? W1[(size_t)n * F_IN + k] : 0.f);
    } else if ((idx -= P_W1) < P_W2) {
        W2b[idx] = __float2bfloat16(W2[idx]);
    } else if ((idx -= P_W2) < P_WHH4) {
        int np = idx / KEXT, k = idx % KEXT;
        int w = np >> 6, nf = (np >> 4) & 3, l4 = (np >> 2) & 3, r = np & 3;
        int u = w * 16 + nf * 4 + l4;
        int j = r * H_RNN + u;
        float v = 0.f;
        if (k < 128)       v = W_hh[(size_t)j * H_RNN + k];
        else if (k < 153)  v = W_ih[j * 25 + (k - 128)];
        else if (k == 153) v = b_ih[j] + b_hh[j];
        Whh4[idx] = __float2bfloat16(v);
    } else {
        idx -= P_WHH4;
        int t = idx >> 5, kk = idx & 31;
        float v = 0.f;
        if (kk < 25)       v = features[(size_t)t * F_IN + (kk == 0 ? 0 : 48 + kk)];
        else if (kk == 25) v = 1.f;
        Xd[idx] = __float2bfloat16(v);
    }
}

// ---------------- FNN via bf16 MFMA (validated R22: in-register A cast) ----------------

__global__ __launch_bounds__(512, 2) void fnn_mfma(
    const float* __restrict__ features,
    const __hip_bfloat16* __restrict__ W1bf,
    const float* __restrict__ b1,
    const __hip_bfloat16* __restrict__ W2bf,
    const float* __restrict__ b2,
    float* __restrict__ out)
{
    __shared__ __attribute__((aligned(16))) unsigned char smem[66560];
    __hip_bfloat16 (*c1)[520] = reinterpret_cast<__hip_bfloat16(*)[520]>(smem);
    float          (*fb)[260] = reinterpret_cast<float(*)[260]>(smem);

    const int tid  = threadIdx.x;
    const int wid  = tid >> 6;
    const int lane = tid & 63;
    const int lr   = lane & 15;
    const int lg   = lane >> 4;
    const int wm   = wid >> 2;
    const int wn   = wid & 3;
    const int m0   = blockIdx.x * 64;

    bf16x8 afrag[3][2];
#pragma unroll
    for (int ks = 0; ks < 3; ++ks)
#pragma unroll
        for (int mf = 0; mf < 2; ++mf) {
            const int row = m0 + wm * 32 + mf * 16 + lr;
            const int k0  = ks * 32 + lg * 8;
            bf16x8 t;
#pragma unroll
            for (int j = 0; j < 8; ++j) {
                int k = k0 + j;
                float v = (k < F_IN) ? features[(size_t)row * F_IN + k] : 0.f;
                __hip_bfloat16 hb = __float2bfloat16(v);
                t[j] = *reinterpret_cast<short*>(&hb);
            }
            afrag[ks][mf] = t;
        }

    f32x4 acc1[2][8];
#pragma unroll
    for (int i = 0; i < 2; ++i)
#pragma unroll
        for (int j = 0; j < 8; ++j)
            acc1[i][j] = (f32x4){0.f, 0.f, 0.f, 0.f};

#pragma unroll
    for (int ks = 0; ks < 3; ++ks) {
        const int k0 = ks * 32 + lg * 8;
        bf16x8 b[8];
#pragma unroll
        for (int nf = 0; nf < 8; ++nf) {
            const int col = wn * 128 + nf * 16 + lr;
            b[nf] = *reinterpret_cast<const bf16x8*>(W1bf + (size_t)col * KP1 + k0);
        }
#pragma unroll
        for (int mf = 0; mf < 2; ++mf)
#pragma unroll
            for (int nf = 0; nf < 8; ++nf)
                acc1[mf][nf] = __builtin_amdgcn_mfma_f32_16x16x32_bf16(
                    afrag[ks][mf], b[nf], acc1[mf][nf], 0, 0, 0);
    }

#pragma unroll
    for (int nf = 0; nf < 8; ++nf) {
        const int col = wn * 128 + nf * 16 + lr;
        const float bv = b1[col];
#pragma unroll
        for (int mf = 0; mf < 2; ++mf) {
            const int rowb = wm * 32 + mf * 16 + lg * 4;
#pragma unroll
            for (int r = 0; r < 4; ++r) {
                float v = fmaxf(acc1[mf][nf][r] + bv, 0.f);
                c1[rowb + r][col] = __float2bfloat16(v);
            }
        }
    }
    __syncthreads();

    f32x4 acc2[2][4];
#pragma unroll
    for (int i = 0; i < 2; ++i)
#pragma unroll
        for (int j = 0; j < 4; ++j)
            acc2[i][j] = (f32x4){0.f, 0.f, 0.f, 0.f};

#pragma unroll
    for (int ks = 0; ks < 16; ++ks) {
        const int k0 = ks * 32 + lg * 8;
        bf16x8 a[2], b[4];
#pragma unroll
        for (int mf = 0; mf < 2; ++mf) {
            const int row = wm * 32 + mf * 16 + lr;
            a[mf] = *reinterpret_cast<const bf16x8*>(&c1[row][k0]);
        }
#pragma unroll
        for (int nf = 0; nf < 4; ++nf) {
            const int col = wn * 64 + nf * 16 + lr;
            b[nf] = *reinterpret_cast<const bf16x8*>(W2bf + (size_t)col * H_FNN + k0);
        }
#pragma unroll
        for (int mf = 0; mf < 2; ++mf)
#pragma unroll
            for (int nf = 0; nf < 4; ++nf)
                acc2[mf][nf] = __builtin_amdgcn_mfma_f32_16x16x32_bf16(
                    a[mf], b[nf], acc2[mf][nf], 0, 0, 0);
    }
    __syncthreads();   // all c1 reads done; region becomes fb

#pragma unroll
    for (int nf = 0; nf < 4; ++nf) {
        const int col = wn * 64 + nf * 16 + lr;
        const float bv = b2[col];
#pragma unroll
        for (int mf = 0; mf < 2; ++mf) {
            const int rowb = wm * 32 + mf * 16 + lg * 4;
#pragma unroll
            for (int r = 0; r < 4; ++r)
                fb[rowb + r][col] = fmaxf(acc2[mf][nf][r] + bv, 0.f);
        }
    }
    __syncthreads();

#pragma unroll
    for (int k = 0; k < 8; ++k) {
        int idx = k * 512 + tid;                 // 0..4095 float4s
        int row = idx >> 6, c4 = (idx & 63) * 4;
        float4 v = *reinterpret_cast<const float4*>(&fb[row][c4]);
        size_t rr = (size_t)(m0 + row);
        *reinterpret_cast<float4*>(out + rr * OUT_COLS + c4) = v;
        *reinterpret_cast<float4*>(out + ((size_t)T_TOTAL + rr) * OUT_COLS + c4) = v;
    }
}

// ---------------- K=160 MFMA LSTM (R20/R22 structure + T5 setprio on MFMA) ----------------
// Single lever this round: s_setprio(1) around the MFMA cluster. Prerequisite
// check (catalog T5): 2 INDEPENDENT blocks/CU at uncorrelated phases -- when
// block A's waves enter MFMA while block B's issue update VALU/trans on the
// same SIMD, priority arbitration can favor the matrix pipe. (m190's null was
// a single lockstep block; our structure matches the attn case, +4-7%.)

__global__ __attribute__((amdgpu_flat_work_group_size(512, 512),
                          amdgpu_waves_per_eu(4, 4)))
void lstm_mfma17(
    const __hip_bfloat16* __restrict__ Xd,     // [T][32]
    const __hip_bfloat16* __restrict__ Whh4,   // [512][160] rows n'
    float* __restrict__ out)
{
    const int tid = threadIdx.x;
    const int l   = tid & 63;
    const int w   = tid >> 6;          // wave 0..7
    const int lr  = l & 15;            // chain 0..15 (MFMA D column)
    const int lg  = l >> 4;            // 0..3

    __shared__ __attribute__((aligned(16))) __hip_bfloat16 hB[2][CPB][HBROW];     // 11.5 KiB
    __shared__ __attribute__((aligned(8))) unsigned short outb[CPB][SEG][OBROW];  // 16.75 KiB

    bf16x8 afr[4][5];
#pragma unroll
    for (int nf = 0; nf < 4; ++nf)
#pragma unroll
        for (int ks = 0; ks < 5; ++ks)
            afr[nf][ks] = *reinterpret_cast<const bf16x8*>(
                Whh4 + (size_t)(w * 64 + nf * 16 + lr) * KEXT + ks * 32 + lg * 8);

    const int tbase = blockIdx.x * (CPB * SEG) - BURN;
    const int tb_c  = tbase + lr * SEG;

    const int xch  = l >> 2;
    const int xp   = l & 3;
    const int tb_x = tbase + xch * SEG;
    auto xdload = [&](int t) -> uint4 {
        int tc = t < 0 ? 0 : (t > T_TOTAL - 1 ? T_TOTAL - 1 : t);
        return *reinterpret_cast<const uint4*>(
            (const char*)Xd + (size_t)tc * 64 + xp * 16);
    };

    {
        uint32_t* hz = (uint32_t*)&hB[0][0][0];
        for (int k = tid; k < 2944; k += 512) hz[k] = 0u;
    }
    uint4 xq = {0u, 0u, 0u, 0u};
    if (w == 0) {
        uint4 x0 = xdload(tb_x + 0);
        *reinterpret_cast<uint4*>(&hB[0][xch][128 + xp * 8]) = x0;
        xq = xdload(tb_x + 1);
    }

    float c_st[4] = {0.f, 0.f, 0.f, 0.f};
    __syncthreads();

#pragma unroll
    for (int i = 0; i < STEPS; ++i) {
        const int pb = i & 1;

        bf16x8 bfrg[5];
#pragma unroll
        for (int ks = 0; ks < 5; ++ks)
            bfrg[ks] = *reinterpret_cast<const bf16x8*>(&hB[pb][lr][ks * 32 + lg * 8]);

        f32x4 acc[4];
#pragma unroll
        for (int nf = 0; nf < 4; ++nf) acc[nf] = (f32x4){0.f, 0.f, 0.f, 0.f};

        __builtin_amdgcn_s_setprio(1);           // T5: favor the MFMA cluster
#pragma unroll
        for (int nf = 0; nf < 4; ++nf)
#pragma unroll
            for (int ks = 0; ks < 5; ++ks)
                acc[nf] = __builtin_amdgcn_mfma_f32_16x16x32_bf16(
                    afr[nf][ks], bfrg[ks], acc[nf], 0, 0, 0);
        __builtin_amdgcn_s_setprio(0);

        const bool neg = (tb_c + i) < 0;
#pragma unroll
        for (int nf = 0; nf < 4; ++nf) {
            float I = fast_sigmoid(acc[nf][0]);
            float F = fast_sigmoid(acc[nf][1]);
            float G = fast_tanh  (acc[nf][2]);
            float O = fast_sigmoid(acc[nf][3]);
            float cn = F * c_st[nf] + I * G;
            c_st[nf] = neg ? 0.f : cn;
            float h  = neg ? 0.f : O * fast_tanh(c_st[nf]);
            const int u = w * 16 + nf * 4 + lg;
            hB[pb ^ 1][lr][u] = __float2bfloat16(h);
            if (i >= BURN) {
                __hip_bfloat16 hb = __float2bfloat16(fmaxf(h, 0.f));
                outb[lr][i - BURN][u] = *reinterpret_cast<unsigned short*>(&hb);
            }
        }

        if (w == 0) {
            *reinterpret_cast<uint4*>(&hB[pb ^ 1][xch][128 + xp * 8]) = xq;
            xq = xdload(tb_x + i + 2);
        }

        asm volatile("s_waitcnt lgkmcnt(0)" ::: "memory");
        __builtin_amdgcn_s_barrier();
        __builtin_amdgcn_sched_barrier(0);
    }

    // ---- tail: outb (LDS) -> coalesced global stream, both tuple copies ----
    const unsigned int* ob32 = reinterpret_cast<const unsigned int*>(&outb[0][0][0]);
#pragma unroll
    for (int k = 0; k < 8; ++k) {
        int idx  = k * 512 + tid;               // 0..4095 data dwords
        int row  = idx >> 6;                    // lr*SEG + st   (64 rows)
        int cold = idx & 63;                    // unit pair
        unsigned int v2 = ob32[row * (OBROW / 2) + cold];
        float v0 = __uint_as_float(v2 << 16);
        float v1 = __uint_as_float(v2 & 0xffff0000u);
        size_t t = (size_t)blockIdx.x * (CPB * SEG) + row;
        float2* po = reinterpret_cast<float2*>(out + t * OUT_COLS + 256 + 2 * cold);
        *po = make_float2(v0, v1);
        po = reinterpret_cast<float2*>(out + ((size_t)T_TOTAL + t) * OUT_COLS + 256 + 2 * cold);
        *po = make_float2(v0, v1);
    }
}

// ---------------- host ----------------

extern "C" void kernel_launch(void* const* d_in, const int* in_sizes, int n_in,
                              void* d_out, int out_size, void* d_ws, size_t ws_size,
                              hipStream_t stream) {
    const float* features = (const float*)d_in[0];
    const float* W1   = (const float*)d_in[1];
    const float* b1   = (const float*)d_in[2];
    const float* W2   = (const float*)d_in[3];
    const float* b2   = (const float*)d_in[4];
    const float* W_ih = (const float*)d_in[5];
    const float* b_ih = (const float*)d_in[6];
    const float* W_hh = (const float*)d_in[7];
    const float* b_hh = (const float*)d_in[8];
    float* out = (float*)d_out;

    char* ws = (char*)d_ws;
    size_t off = 0;
    __hip_bfloat16* W1b  = (__hip_bfloat16*)(ws + off); off += (size_t)P_W1 * 2;
    __hip_bfloat16* W2b  = (__hip_bfloat16*)(ws + off); off += (size_t)P_W2 * 2;
    __hip_bfloat16* Whh4 = (__hip_bfloat16*)(ws + off); off += (size_t)P_WHH4 * 2;
    __hip_bfloat16* Xd   = (__hip_bfloat16*)(ws + off);

    hipLaunchKernelGGL(prep_kernel, dim3((P_TOT + 255) / 256), dim3(256), 0, stream,
                       features, W1, W2, W_hh, W_ih, b_ih, b_hh,
                       W1b, W2b, Whh4, Xd);
    hipLaunchKernelGGL(fnn_mfma,    dim3(T_TOTAL / 64), dim3(512), 0, stream,
                       features, W1b, b1, W2b, b2, out);
    hipLaunchKernelGGL(lstm_mfma17, dim3(NLSTM), dim3(512), 0, stream, Xd, Whh4, out);
}

// Round 24
// 120.113 us; speedup vs baseline: 1.0323x; 1.0323x over previous
//
#include <hip/hip_runtime.h>
#include <hip/hip_bf16.h>
#include <cstdint>
#include <cstddef>

#define T_TOTAL 32768
#define F_IN    73
#define H_FNN   512
#define D_FNN   256
#define H_RNN   128
#define G4      512
#define SEG     4
#define BURN    28
#define STEPS   (SEG + BURN)      // 32
#define CPB     16               // chains per lstm block (one per MFMA D-column)
#define NLSTM   512              // 512 x 16 chains x 4 steps = 32768
#define KEXT    160              // 128 (h) + 32 (x block: 25 feats + bias + pad)
#define HBROW   184              // hB row stride (92 dwords = 28 mod 32 -> <=2-way banks)
#define OBROW   134              // outb row stride in shorts (67 dwords = 3 mod 32)
#define OUT_COLS 384
#define KP1     96

typedef short bf16x8 __attribute__((ext_vector_type(8)));
typedef float f32x4  __attribute__((ext_vector_type(4)));

// ---------------- helpers ----------------

__device__ __forceinline__ float fast_sigmoid(float x) {
    float e = __expf(-x);
    return __builtin_amdgcn_rcpf(1.f + e);
}
__device__ __forceinline__ float fast_tanh(float x) {
    float e = __expf(2.f * x);
    return 1.f - 2.f * __builtin_amdgcn_rcpf(e + 1.f);
}

// ---------------- prep: W1b, W2b, Whh4 (K=160 concat), Xd (validated R22) ----------------

#define P_W1   (H_FNN * KP1)       // 49152
#define P_W2   (D_FNN * H_FNN)     // 131072
#define P_WHH4 (G4 * KEXT)         // 81920
#define P_XD   (T_TOTAL * 32)      // 1048576
#define P_TOT  (P_W1 + P_W2 + P_WHH4 + P_XD)

__global__ void prep_kernel(
    const float* __restrict__ features, const float* __restrict__ W1,
    const float* __restrict__ W2,       const float* __restrict__ W_hh,
    const float* __restrict__ W_ih,     const float* __restrict__ b_ih,
    const float* __restrict__ b_hh,
    __hip_bfloat16* __restrict__ W1b,   __hip_bfloat16* __restrict__ W2b,
    __hip_bfloat16* __restrict__ Whh4,  __hip_bfloat16* __restrict__ Xd)
{
    int idx = blockIdx.x * 256 + threadIdx.x;
    if (idx >= P_TOT) return;
    if (idx < P_W1) {
        int n = idx / KP1, k = idx % KP1;
        W1b[idx] = __float2bfloat16(k < F_IN ? W1[(size_t)n * F_IN + k] : 0.f);
    } else if ((idx -= P_W1) < P_W2) {
        W2b[idx] = __float2bfloat16(W2[idx]);
    } else if ((idx -= P_W2) < P_WHH4) {
        int np = idx / KEXT, k = idx % KEXT;
        int w = np >> 6, nf = (np >> 4) & 3, l4 = (np >> 2) & 3, r = np & 3;
        int u = w * 16 + nf * 4 + l4;
        int j = r * H_RNN + u;
        float v = 0.f;
        if (k < 128)       v = W_hh[(size_t)j * H_RNN + k];
        else if (k < 153)  v = W_ih[j * 25 + (k - 128)];
        else if (k == 153) v = b_ih[j] + b_hh[j];
        Whh4[idx] = __float2bfloat16(v);
    } else {
        idx -= P_WHH4;
        int t = idx >> 5, kk = idx & 31;
        float v = 0.f;
        if (kk < 25)       v = features[(size_t)t * F_IN + (kk == 0 ? 0 : 48 + kk)];
        else if (kk == 25) v = 1.f;
        Xd[idx] = __float2bfloat16(v);
    }
}

// ---------------- FNN via bf16 MFMA (validated R22: in-register A cast) ----------------

__global__ __launch_bounds__(512, 2) void fnn_mfma(
    const float* __restrict__ features,
    const __hip_bfloat16* __restrict__ W1bf,
    const float* __restrict__ b1,
    const __hip_bfloat16* __restrict__ W2bf,
    const float* __restrict__ b2,
    float* __restrict__ out)
{
    __shared__ __attribute__((aligned(16))) unsigned char smem[66560];
    __hip_bfloat16 (*c1)[520] = reinterpret_cast<__hip_bfloat16(*)[520]>(smem);
    float          (*fb)[260] = reinterpret_cast<float(*)[260]>(smem);

    const int tid  = threadIdx.x;
    const int wid  = tid >> 6;
    const int lane = tid & 63;
    const int lr   = lane & 15;
    const int lg   = lane >> 4;
    const int wm   = wid >> 2;
    const int wn   = wid & 3;
    const int m0   = blockIdx.x * 64;

    bf16x8 afrag[3][2];
#pragma unroll
    for (int ks = 0; ks < 3; ++ks)
#pragma unroll
        for (int mf = 0; mf < 2; ++mf) {
            const int row = m0 + wm * 32 + mf * 16 + lr;
            const int k0  = ks * 32 + lg * 8;
            bf16x8 t;
#pragma unroll
            for (int j = 0; j < 8; ++j) {
                int k = k0 + j;
                float v = (k < F_IN) ? features[(size_t)row * F_IN + k] : 0.f;
                __hip_bfloat16 hb = __float2bfloat16(v);
                t[j] = *reinterpret_cast<short*>(&hb);
            }
            afrag[ks][mf] = t;
        }

    f32x4 acc1[2][8];
#pragma unroll
    for (int i = 0; i < 2; ++i)
#pragma unroll
        for (int j = 0; j < 8; ++j)
            acc1[i][j] = (f32x4){0.f, 0.f, 0.f, 0.f};

#pragma unroll
    for (int ks = 0; ks < 3; ++ks) {
        const int k0 = ks * 32 + lg * 8;
        bf16x8 b[8];
#pragma unroll
        for (int nf = 0; nf < 8; ++nf) {
            const int col = wn * 128 + nf * 16 + lr;
            b[nf] = *reinterpret_cast<const bf16x8*>(W1bf + (size_t)col * KP1 + k0);
        }
#pragma unroll
        for (int mf = 0; mf < 2; ++mf)
#pragma unroll
            for (int nf = 0; nf < 8; ++nf)
                acc1[mf][nf] = __builtin_amdgcn_mfma_f32_16x16x32_bf16(
                    afrag[ks][mf], b[nf], acc1[mf][nf], 0, 0, 0);
    }

#pragma unroll
    for (int nf = 0; nf < 8; ++nf) {
        const int col = wn * 128 + nf * 16 + lr;
        const float bv = b1[col];
#pragma unroll
        for (int mf = 0; mf < 2; ++mf) {
            const int rowb = wm * 32 + mf * 16 + lg * 4;
#pragma unroll
            for (int r = 0; r < 4; ++r) {
                float v = fmaxf(acc1[mf][nf][r] + bv, 0.f);
                c1[rowb + r][col] = __float2bfloat16(v);
            }
        }
    }
    __syncthreads();

    f32x4 acc2[2][4];
#pragma unroll
    for (int i = 0; i < 2; ++i)
#pragma unroll
        for (int j = 0; j < 4; ++j)
            acc2[i][j] = (f32x4){0.f, 0.f, 0.f, 0.f};

#pragma unroll
    for (int ks = 0; ks < 16; ++ks) {
        const int k0 = ks * 32 + lg * 8;
        bf16x8 a[2], b[4];
#pragma unroll
        for (int mf = 0; mf < 2; ++mf) {
            const int row = wm * 32 + mf * 16 + lr;
            a[mf] = *reinterpret_cast<const bf16x8*>(&c1[row][k0]);
        }
#pragma unroll
        for (int nf = 0; nf < 4; ++nf) {
            const int col = wn * 64 + nf * 16 + lr;
            b[nf] = *reinterpret_cast<const bf16x8*>(W2bf + (size_t)col * H_FNN + k0);
        }
#pragma unroll
        for (int mf = 0; mf < 2; ++mf)
#pragma unroll
            for (int nf = 0; nf < 4; ++nf)
                acc2[mf][nf] = __builtin_amdgcn_mfma_f32_16x16x32_bf16(
                    a[mf], b[nf], acc2[mf][nf], 0, 0, 0);
    }
    __syncthreads();   // all c1 reads done; region becomes fb

#pragma unroll
    for (int nf = 0; nf < 4; ++nf) {
        const int col = wn * 64 + nf * 16 + lr;
        const float bv = b2[col];
#pragma unroll
        for (int mf = 0; mf < 2; ++mf) {
            const int rowb = wm * 32 + mf * 16 + lg * 4;
#pragma unroll
            for (int r = 0; r < 4; ++r)
                fb[rowb + r][col] = fmaxf(acc2[mf][nf][r] + bv, 0.f);
        }
    }
    __syncthreads();

#pragma unroll
    for (int k = 0; k < 8; ++k) {
        int idx = k * 512 + tid;                 // 0..4095 float4s
        int row = idx >> 6, c4 = (idx & 63) * 4;
        float4 v = *reinterpret_cast<const float4*>(&fb[row][c4]);
        size_t rr = (size_t)(m0 + row);
        *reinterpret_cast<float4*>(out + rr * OUT_COLS + c4) = v;
        *reinterpret_cast<float4*>(out + ((size_t)T_TOTAL + rr) * OUT_COLS + c4) = v;
    }
}

// ---------------- K=160 MFMA LSTM, 16 chains/block (R20/R22 verbatim) ----------------
// R23 lesson: T5 setprio around the MFMA cluster REGRESSED 69.8->74.7us (the
// barrier convoy keeps co-resident blocks loosely phase-locked; boosting MFMA
// waves just delays the other block's update issue). Reverted. This is the
// measured-best lstm configuration; its 2.18us/step is a serial-dependency
// latency floor, not a pipe roofline (MfmaUtil 24%, VALUBusy 57%, HBM 7%).

__global__ __attribute__((amdgpu_flat_work_group_size(512, 512),
                          amdgpu_waves_per_eu(4, 4)))
void lstm_mfma18(
    const __hip_bfloat16* __restrict__ Xd,     // [T][32]
    const __hip_bfloat16* __restrict__ Whh4,   // [512][160] rows n'
    float* __restrict__ out)
{
    const int tid = threadIdx.x;
    const int l   = tid & 63;
    const int w   = tid >> 6;          // wave 0..7
    const int lr  = l & 15;            // chain 0..15 (MFMA D column)
    const int lg  = l >> 4;            // 0..3

    __shared__ __attribute__((aligned(16))) __hip_bfloat16 hB[2][CPB][HBROW];     // 11.5 KiB
    __shared__ __attribute__((aligned(8))) unsigned short outb[CPB][SEG][OBROW];  // 16.75 KiB

    bf16x8 afr[4][5];
#pragma unroll
    for (int nf = 0; nf < 4; ++nf)
#pragma unroll
        for (int ks = 0; ks < 5; ++ks)
            afr[nf][ks] = *reinterpret_cast<const bf16x8*>(
                Whh4 + (size_t)(w * 64 + nf * 16 + lr) * KEXT + ks * 32 + lg * 8);

    const int tbase = blockIdx.x * (CPB * SEG) - BURN;
    const int tb_c  = tbase + lr * SEG;

    const int xch  = l >> 2;
    const int xp   = l & 3;
    const int tb_x = tbase + xch * SEG;
    auto xdload = [&](int t) -> uint4 {
        int tc = t < 0 ? 0 : (t > T_TOTAL - 1 ? T_TOTAL - 1 : t);
        return *reinterpret_cast<const uint4*>(
            (const char*)Xd + (size_t)tc * 64 + xp * 16);
    };

    {
        uint32_t* hz = (uint32_t*)&hB[0][0][0];
        for (int k = tid; k < 2944; k += 512) hz[k] = 0u;
    }
    uint4 xq = {0u, 0u, 0u, 0u};
    if (w == 0) {
        uint4 x0 = xdload(tb_x + 0);
        *reinterpret_cast<uint4*>(&hB[0][xch][128 + xp * 8]) = x0;
        xq = xdload(tb_x + 1);
    }

    float c_st[4] = {0.f, 0.f, 0.f, 0.f};
    __syncthreads();

#pragma unroll
    for (int i = 0; i < STEPS; ++i) {
        const int pb = i & 1;

        bf16x8 bfrg[5];
#pragma unroll
        for (int ks = 0; ks < 5; ++ks)
            bfrg[ks] = *reinterpret_cast<const bf16x8*>(&hB[pb][lr][ks * 32 + lg * 8]);

        f32x4 acc[4];
#pragma unroll
        for (int nf = 0; nf < 4; ++nf) acc[nf] = (f32x4){0.f, 0.f, 0.f, 0.f};
#pragma unroll
        for (int nf = 0; nf < 4; ++nf)
#pragma unroll
            for (int ks = 0; ks < 5; ++ks)
                acc[nf] = __builtin_amdgcn_mfma_f32_16x16x32_bf16(
                    afr[nf][ks], bfrg[ks], acc[nf], 0, 0, 0);

        const bool neg = (tb_c + i) < 0;
#pragma unroll
        for (int nf = 0; nf < 4; ++nf) {
            float I = fast_sigmoid(acc[nf][0]);
            float F = fast_sigmoid(acc[nf][1]);
            float G = fast_tanh  (acc[nf][2]);
            float O = fast_sigmoid(acc[nf][3]);
            float cn = F * c_st[nf] + I * G;
            c_st[nf] = neg ? 0.f : cn;
            float h  = neg ? 0.f : O * fast_tanh(c_st[nf]);
            const int u = w * 16 + nf * 4 + lg;
            hB[pb ^ 1][lr][u] = __float2bfloat16(h);
            if (i >= BURN) {
                __hip_bfloat16 hb = __float2bfloat16(fmaxf(h, 0.f));
                outb[lr][i - BURN][u] = *reinterpret_cast<unsigned short*>(&hb);
            }
        }

        if (w == 0) {
            *reinterpret_cast<uint4*>(&hB[pb ^ 1][xch][128 + xp * 8]) = xq;
            xq = xdload(tb_x + i + 2);
        }

        asm volatile("s_waitcnt lgkmcnt(0)" ::: "memory");
        __builtin_amdgcn_s_barrier();
        __builtin_amdgcn_sched_barrier(0);
    }

    // ---- tail: outb (LDS) -> coalesced global stream, both tuple copies ----
    const unsigned int* ob32 = reinterpret_cast<const unsigned int*>(&outb[0][0][0]);
#pragma unroll
    for (int k = 0; k < 8; ++k) {
        int idx  = k * 512 + tid;               // 0..4095 data dwords
        int row  = idx >> 6;                    // lr*SEG + st   (64 rows)
        int cold = idx & 63;                    // unit pair
        unsigned int v2 = ob32[row * (OBROW / 2) + cold];
        float v0 = __uint_as_float(v2 << 16);
        float v1 = __uint_as_float(v2 & 0xffff0000u);
        size_t t = (size_t)blockIdx.x * (CPB * SEG) + row;
        float2* po = reinterpret_cast<float2*>(out + t * OUT_COLS + 256 + 2 * cold);
        *po = make_float2(v0, v1);
        po = reinterpret_cast<float2*>(out + ((size_t)T_TOTAL + t) * OUT_COLS + 256 + 2 * cold);
        *po = make_float2(v0, v1);
    }
}

// ---------------- host ----------------

extern "C" void kernel_launch(void* const* d_in, const int* in_sizes, int n_in,
                              void* d_out, int out_size, void* d_ws, size_t ws_size,
                              hipStream_t stream) {
    const float* features = (const float*)d_in[0];
    const float* W1   = (const float*)d_in[1];
    const float* b1   = (const float*)d_in[2];
    const float* W2   = (const float*)d_in[3];
    const float* b2   = (const float*)d_in[4];
    const float* W_ih = (const float*)d_in[5];
    const float* b_ih = (const float*)d_in[6];
    const float* W_hh = (const float*)d_in[7];
    const float* b_hh = (const float*)d_in[8];
    float* out = (float*)d_out;

    char* ws = (char*)d_ws;
    size_t off = 0;
    __hip_bfloat16* W1b  = (__hip_bfloat16*)(ws + off); off += (size_t)P_W1 * 2;
    __hip_bfloat16* W2b  = (__hip_bfloat16*)(ws + off); off += (size_t)P_W2 * 2;
    __hip_bfloat16* Whh4 = (__hip_bfloat16*)(ws + off); off += (size_t)P_WHH4 * 2;
    __hip_bfloat16* Xd   = (__hip_bfloat16*)(ws + off);

    hipLaunchKernelGGL(prep_kernel, dim3((P_TOT + 255) / 256), dim3(256), 0, stream,
                       features, W1, W2, W_hh, W_ih, b_ih, b_hh,
                       W1b, W2b, Whh4, Xd);
    hipLaunchKernelGGL(fnn_mfma,    dim3(T_TOTAL / 64), dim3(512), 0, stream,
                       features, W1b, b1, W2b, b2, out);
    hipLaunchKernelGGL(lstm_mfma18, dim3(NLSTM), dim3(512), 0, stream, Xd, Whh4, out);
}